// Round 3
// baseline (896.733 us; speedup 1.0000x reference)
//
#include <hip/hip_runtime.h>

// Problem constants (B=1 folded out)
constexpr int C  = 64;
constexpr int D  = 64;
constexpr int H  = 128;
constexpr int W  = 128;
constexpr int ZS = H * W;       // 16384   (z stride, elements)
constexpr int YS = W;           // 128     (y stride)
constexpr int CS = D * H * W;   // 1048576 (channel stride)

// Native clang vector type: accepted by __builtin_nontemporal_{load,store}.
typedef float f4 __attribute__((ext_vector_type(4)));

// One thread computes 4 consecutive x outputs for all 27 displacement taps.
//
// Round-2 lesson: acc[27][4] pins 108 VGPRs, so every extra live load
// destination is precious. This version cuts VMEM instructions per channel
// iteration from 28 to 10:
//   - 9 row float4 loads (branch-free: clamped address + 0/1 row mask)
//   - 1 in1 float4 load (non-temporal; single-use stream)
//   - the 18 x-edge scalar loads are replaced by cross-lane shuffles:
//       v0 = in2[x0-1] = lane(tx-1).m.w  -> __shfl_up(m.w, 1, 32)
//       v5 = in2[x0+4] = lane(tx+1).m.x  -> __shfl_down(m.x, 1, 32)
//     Segment-boundary lanes (tx==0 / tx==31) receive garbage, but those are
//     exactly the x-edge positions whose mask (mlo/mhi) is 0. Row validity
//     masks are identical across lanes of the same y-row, so the shuffled
//     value carries the same rowmask treatment via the masked in1 fragment.
__global__ __launch_bounds__(256, 2)
void corr3d_kernel(const float* __restrict__ in1,
                   const float* __restrict__ in2,
                   float* __restrict__ out) {
    const int tx = threadIdx.x;           // 0..31 -> x0 = 4*tx
    const int ty = threadIdx.y;           // 0..7
    const int x0 = tx * 4;
    const int y  = blockIdx.x * 8 + ty;   // 0..127
    const int z  = blockIdx.y;            // 0..63

    float acc[27][4];
#pragma unroll
    for (int j = 0; j < 27; ++j) {
#pragma unroll
        for (int i = 0; i < 4; ++i) acc[j][i] = 0.0f;
    }

    // Per-row (dz,dy) descriptors: clamped base offset + 0/1 validity mask.
    int   rowoff[9];
    float rowmask[9];
#pragma unroll
    for (int dz = 0; dz < 3; ++dz) {
        const int zz  = z + dz - 1;
        const int zzc = min(max(zz, 0), D - 1);
        const bool zok = ((unsigned)zz < (unsigned)D);
#pragma unroll
        for (int dy = 0; dy < 3; ++dy) {
            const int yy  = y + dy - 1;
            const int yyc = min(max(yy, 0), H - 1);
            const bool ok = zok && ((unsigned)yy < (unsigned)H);
            const int r = dz * 3 + dy;
            rowoff[r]  = zzc * ZS + yyc * YS + x0;
            rowmask[r] = ok ? 1.0f : 0.0f;
        }
    }

    // x-edge masks (the only edge handling needed for dx taps now).
    const float mlo = (x0 > 0)     ? 1.0f : 0.0f;
    const float mhi = (x0 < W - 4) ? 1.0f : 0.0f;

    const float* p1 = in1 + z * ZS + y * YS + x0;

    for (int c = 0; c < C; ++c) {
        const float* b2 = in2 + c * CS;

        // in1 fragment: touched by exactly one thread -> non-temporal.
        const f4 a = __builtin_nontemporal_load((const f4*)(p1 + c * CS));

        // ---- load phase: 9 independent row loads, no branches ----
        f4 m[9];
#pragma unroll
        for (int r = 0; r < 9; ++r) {
            m[r] = *(const f4*)(b2 + rowoff[r]);
        }

        // ---- compute phase: shuffles + 108 FMAs ----
#pragma unroll
        for (int r = 0; r < 9; ++r) {
            const float msk = rowmask[r];
            const float ax = a.x * msk, ay = a.y * msk,
                        az = a.z * msk, aw = a.w * msk;
            const float v1 = m[r].x, v2 = m[r].y, v3 = m[r].z, v4 = m[r].w;
            const float v0 = __shfl_up(v4, 1, 32) * mlo;   // neighbor's m.w
            const float v5 = __shfl_down(v1, 1, 32) * mhi; // neighbor's m.x
            const int jb = r * 3;

            acc[jb + 0][0] += ax * v0;
            acc[jb + 0][1] += ay * v1;
            acc[jb + 0][2] += az * v2;
            acc[jb + 0][3] += aw * v3;

            acc[jb + 1][0] += ax * v1;
            acc[jb + 1][1] += ay * v2;
            acc[jb + 1][2] += az * v3;
            acc[jb + 1][3] += aw * v4;

            acc[jb + 2][0] += ax * v2;
            acc[jb + 2][1] += ay * v3;
            acc[jb + 2][2] += az * v4;
            acc[jb + 2][3] += aw * v5;
        }
    }

    const float s = 1.0f / (float)C;  // channel mean
    float* po = out + z * ZS + y * YS + x0;
#pragma unroll
    for (int j = 0; j < 27; ++j) {
        f4 o;
        o.x = acc[j][0] * s;
        o.y = acc[j][1] * s;
        o.z = acc[j][2] * s;
        o.w = acc[j][3] * s;
        // out is written once and never re-read -> non-temporal store.
        __builtin_nontemporal_store(o, (f4*)(po + (size_t)j * CS));
    }
}

extern "C" void kernel_launch(void* const* d_in, const int* in_sizes, int n_in,
                              void* d_out, int out_size, void* d_ws, size_t ws_size,
                              hipStream_t stream) {
    const float* in1 = (const float*)d_in[0];
    const float* in2 = (const float*)d_in[1];
    float* out = (float*)d_out;

    dim3 block(32, 8);        // 256 threads = 4 waves; wave = 2 y-rows
    dim3 grid(H / 8, D);      // (16 y-groups, 64 z)
    corr3d_kernel<<<grid, block, 0, stream>>>(in1, in2, out);
}